// Round 4
// baseline (301.314 us; speedup 1.0000x reference)
//
#include <hip/hip_runtime.h>

#define B_ROWS 4096
#define N_CLUST 1024
#define KDIM 4096
#define KT 64          // k-tiles of 64

#define EMA_OLD 0.01f
#define EMA_NEW 0.99f

typedef unsigned short ushortT;
typedef _Float16 half8 __attribute__((ext_vector_type(8)));
typedef float f32x16 __attribute__((ext_vector_type(16)));

// ---------------- workspace layout (bytes) ----------------
// best[4096] u64 @0, winner[1024] i32 @32768  -> one 0xFF memset (36864 B)
#define WS_BEST_OFF   0
#define WS_WINNER_OFF 32768
#define WS_YY_OFF     36864
#define WS_MM_OFF     53248
#define WS_YHI_OFF    65536
#define WS_YLO_OFF    (WS_YHI_OFF + 33554432)
#define WS_MHI_OFF    (WS_YLO_OFF + 33554432)
#define WS_MLO_OFF    (WS_MHI_OFF + 8388608)
#define WS_REQUIRED   (WS_MLO_OFF + 8388608)  // ~84.2 MB

// one wave per row; rows [0,4096) = y -> yy, rows [4096,5120) = m -> mm.
// Per-row arithmetic bit-identical to rounds 2/3.
__global__ void rowsumsq_all(const float* __restrict__ y,
                             const float* __restrict__ m,
                             float* __restrict__ yy, float* __restrict__ mm) {
    int wave = (blockIdx.x * blockDim.x + threadIdx.x) >> 6;
    int lane = threadIdx.x & 63;
    const float* x;
    float* o;
    if (wave < B_ROWS) {
        x = y + (size_t)wave * KDIM;
        o = yy + wave;
    } else if (wave < B_ROWS + N_CLUST) {
        x = m + (size_t)(wave - B_ROWS) * KDIM;
        o = mm + (wave - B_ROWS);
    } else {
        return;
    }
    const float4* xp = (const float4*)x;
    float s = 0.f;
    for (int i = lane; i < KDIM / 4; i += 64) {
        float4 v = xp[i];
        s += v.x * v.x + v.y * v.y + v.z * v.z + v.w * v.w;
    }
    for (int off = 32; off > 0; off >>= 1) s += __shfl_down(s, off, 64);
    if (lane == 0) *o = s;
}

// ---------------- f16 hi/lo split into tiled+swizzled layout ----------------
// y chunks first (rb_shift=7), then m chunks (rb_shift=6); per-thread math
// identical to rounds 2/3.
#define YCHUNKS (B_ROWS * (KDIM / 8))   // 2,097,152
#define MCHUNKS (N_CLUST * (KDIM / 8))  //   524,288

__global__ void convert_all(const float* __restrict__ ysrc,
                            const float* __restrict__ msrc,
                            ushortT* __restrict__ yhi, ushortT* __restrict__ ylo,
                            ushortT* __restrict__ mhi, ushortT* __restrict__ mlo) {
    int gid = blockIdx.x * blockDim.x + threadIdx.x;
    const float* src;
    ushortT* hi;
    ushortT* lo;
    int cid, rb_shift;
    if (gid < YCHUNKS) {
        src = ysrc; hi = yhi; lo = ylo; cid = gid; rb_shift = 7;
    } else {
        src = msrc; hi = mhi; lo = mlo; cid = gid - YCHUNKS; rb_shift = 6;
        if (cid >= MCHUNKS) return;
    }
    int row = cid >> 9;          // 512 chunks per row (4096/8)
    int ci  = cid & 511;
    int kt  = ci >> 3;
    int p   = ci & 7;
    int r   = row & ((1 << rb_shift) - 1);
    int rb  = row >> rb_shift;
    int c   = p ^ (r & 7);
    const float* s = src + ((size_t)row << 12) + kt * 64 + c * 8;
    float4 v0 = *(const float4*)s;
    float4 v1 = *(const float4*)(s + 4);
    float vv[8] = {v0.x, v0.y, v0.z, v0.w, v1.x, v1.y, v1.z, v1.w};
    half8 hv, lv;
#pragma unroll
    for (int i = 0; i < 8; ++i) {
        _Float16 h = (_Float16)vv[i];
        hv[i] = h;
        lv[i] = (_Float16)(vv[i] - (float)h);
    }
    size_t off = ((size_t)rb * KT + kt) * ((size_t)(1 << rb_shift) * 64)
               + (size_t)r * 64 + p * 8;
    *(half8*)(hi + off) = hv;
    *(half8*)(lo + off) = lv;
}

// ---------------- MFMA distance + fused argmin ----------------
__device__ __forceinline__ void gload_lds16(const void* g, void* l) {
    __builtin_amdgcn_global_load_lds(
        (const __attribute__((address_space(1))) unsigned int*)g,
        (__attribute__((address_space(3))) unsigned int*)l, 16, 0, 0);
}

__device__ __forceinline__ half8 ldfrag(const ushortT* s, int r, int c) {
    int p = c ^ (r & 7);
    return *(const half8*)(s + r * 64 + p * 8);
}

#define MFMA_HH(a, b, c) __builtin_amdgcn_mfma_f32_32x32x16_f16(a, b, c, 0, 0, 0)

// Block tile 64x64, BK=64, LDS 32 KB -> 4 blocks/CU, grid 1024 all-resident.
// 4 waves = 2x2 of 32x32 tiles; per kk: 4 ds_read_b128, 3 MFMA.
// Per-element accumulation chain (hh,hl,lh over kt,kk) bit-identical to r2.
__global__ __launch_bounds__(256, 4) void dist_argmin_mfma(
    const ushortT* __restrict__ Ah, const ushortT* __restrict__ Al,
    const ushortT* __restrict__ Bh, const ushortT* __restrict__ Bl,
    const float* __restrict__ yy, const float* __restrict__ mm,
    unsigned long long* __restrict__ best) {
    __shared__ __align__(16) char smem[32768];
    ushortT* sAh = (ushortT*)smem;               // 8192 B
    ushortT* sAl = (ushortT*)(smem + 8192);      // 8192 B
    ushortT* sBh = (ushortT*)(smem + 16384);     // 8192 B
    ushortT* sBl = (ushortT*)(smem + 24576);     // 8192 B

    const int t = threadIdx.x;
    const int w = t >> 6, l = t & 63;
    const int row0 = blockIdx.x * 64, col0 = blockIdx.y * 64;
    const int rb = blockIdx.x >> 1;          // 128-row block in y layout
    const int half = blockIdx.x & 1;         // which 64-row half
    const int wr = (w >> 1) * 32;            // wave row offset in tile
    const int wc = (w & 1) * 32;             // wave col offset in tile
    const int m0 = l & 31, hsel = l >> 5;

    const char* gAh = (const char*)Ah + (size_t)rb * (KT * 16384) + half * 8192 + l * 16;
    const char* gAl = (const char*)Al + (size_t)rb * (KT * 16384) + half * 8192 + l * 16;
    const char* gBh = (const char*)Bh + (size_t)blockIdx.y * (KT * 8192) + l * 16;
    const char* gBl = (const char*)Bl + (size_t)blockIdx.y * (KT * 8192) + l * 16;

    f32x16 acc;
#pragma unroll
    for (int i = 0; i < 16; ++i) acc[i] = 0.f;

    for (int kt = 0; kt < KT; ++kt) {
        __syncthreads();   // previous tile fully consumed
#pragma unroll
        for (int j = 0; j < 2; ++j) {
            int ch = w * 2 + j;
            gload_lds16(gAh + (size_t)kt * 16384 + ch * 1024, smem + ch * 1024);
            gload_lds16(gAl + (size_t)kt * 16384 + ch * 1024, smem + 8192 + ch * 1024);
            gload_lds16(gBh + (size_t)kt * 8192 + ch * 1024, smem + 16384 + ch * 1024);
            gload_lds16(gBl + (size_t)kt * 8192 + ch * 1024, smem + 24576 + ch * 1024);
        }
        __syncthreads();   // LDS tile ready
#pragma unroll
        for (int kk = 0; kk < 4; ++kk) {
            int c = kk * 2 + hsel;
            half8 ah = ldfrag(sAh, wr + m0, c);
            half8 al = ldfrag(sAl, wr + m0, c);
            half8 bh = ldfrag(sBh, wc + m0, c);
            half8 bl = ldfrag(sBl, wc + m0, c);
            acc = MFMA_HH(ah, bh, acc);
            acc = MFMA_HH(ah, bl, acc);
            acc = MFMA_HH(al, bh, acc);
        }
    }

    // ---- epilogue: d2 + in-register argmin over this wave's 32 cols ----
    const int gcol = col0 + wc + m0;
    const float mmv = mm[gcol];
    unsigned long long key[16];
#pragma unroll
    for (int r = 0; r < 16; ++r) {
        int ri = (r & 3) + 8 * (r >> 2) + 4 * hsel;
        float d2 = yy[row0 + wr + ri] - 2.0f * acc[r] + mmv;
        key[r] = ((unsigned long long)__float_as_uint(d2) << 32) | (unsigned)gcol;
    }
    // xor-shuffle min across 32 lanes (masks <=16 never cross the 32 boundary,
    // and all 32 lanes of one hsel group hold the same 16 rows)
#pragma unroll
    for (int s = 1; s <= 16; s <<= 1) {
#pragma unroll
        for (int r = 0; r < 16; ++r) {
            unsigned long long o = __shfl_xor(key[r], s, 64);
            if (o < key[r]) key[r] = o;
        }
    }
    if (m0 == 0) {
#pragma unroll
        for (int r = 0; r < 16; ++r) {
            int ri = (r & 3) + 8 * (r >> 2) + 4 * hsel;
            atomicMin(&best[row0 + wr + ri], key[r]);
        }
    }
}

// ---------------- fp32 fallback ----------------
#define BM 128
#define BN 64
#define BK 16

__global__ __launch_bounds__(256) void dist_argmin_fp32(
    const float* __restrict__ Y, const float* __restrict__ M,
    const float* __restrict__ yy, const float* __restrict__ mm,
    unsigned long long* __restrict__ best) {
    __shared__ float As[BK][BM + 4];
    __shared__ float Bs[BK][BN + 4];
    __shared__ unsigned long long red[BM];

    const int t = threadIdx.x;
    const int row0 = blockIdx.x * BM;
    const int col0 = blockIdx.y * BN;
    const int srow = t >> 2;
    const int skc  = (t & 3) << 2;
    const int tx = t & 15;
    const int ty = t >> 4;

    const float* aptr0 = Y + (size_t)(row0 + srow) * KDIM + skc;
    const float* aptr1 = Y + (size_t)(row0 + srow + 64) * KDIM + skc;
    const float* bptr  = M + (size_t)(col0 + srow) * KDIM + skc;

    float acc[8][4];
#pragma unroll
    for (int i = 0; i < 8; ++i)
#pragma unroll
        for (int j = 0; j < 4; ++j) acc[i][j] = 0.f;

    for (int k0 = 0; k0 < KDIM; k0 += BK) {
        float4 a0 = *(const float4*)(aptr0 + k0);
        float4 a1 = *(const float4*)(aptr1 + k0);
        float4 bv = *(const float4*)(bptr + k0);
        __syncthreads();
        As[skc + 0][srow] = a0.x; As[skc + 1][srow] = a0.y;
        As[skc + 2][srow] = a0.z; As[skc + 3][srow] = a0.w;
        As[skc + 0][srow + 64] = a1.x; As[skc + 1][srow + 64] = a1.y;
        As[skc + 2][srow + 64] = a1.z; As[skc + 3][srow + 64] = a1.w;
        Bs[skc + 0][srow] = bv.x; Bs[skc + 1][srow] = bv.y;
        Bs[skc + 2][srow] = bv.z; Bs[skc + 3][srow] = bv.w;
        __syncthreads();
#pragma unroll
        for (int k = 0; k < BK; ++k) {
            float4 ar0 = *(const float4*)&As[k][ty * 8];
            float4 ar1 = *(const float4*)&As[k][ty * 8 + 4];
            float4 br  = *(const float4*)&Bs[k][tx * 4];
            const float a[8] = {ar0.x, ar0.y, ar0.z, ar0.w,
                                ar1.x, ar1.y, ar1.z, ar1.w};
            const float b[4] = {br.x, br.y, br.z, br.w};
#pragma unroll
            for (int i = 0; i < 8; ++i)
#pragma unroll
                for (int j = 0; j < 4; ++j) acc[i][j] += a[i] * b[j];
        }
    }
    __syncthreads();
    if (t < BM) red[t] = 0xFFFFFFFFFFFFFFFFull;
    if (t + 128 < BM) red[t + 128] = 0xFFFFFFFFFFFFFFFFull;
    __syncthreads();
#pragma unroll
    for (int i = 0; i < 8; ++i) {
        int lr = ty * 8 + i;
        float yv = yy[row0 + lr];
#pragma unroll
        for (int j = 0; j < 4; ++j) {
            int gc = col0 + tx * 4 + j;
            float d2 = yv - 2.0f * acc[i][j] + mm[gc];
            unsigned long long key =
                ((unsigned long long)__float_as_uint(d2) << 32) | (unsigned)gc;
            atomicMin(&red[lr], key);
        }
    }
    __syncthreads();
    if (t < BM) atomicMin(&best[row0 + t], red[t]);
}

// ---------------- scatter + output ----------------
__global__ void pick_winner(const unsigned long long* __restrict__ best,
                            int* __restrict__ winner) {
    int b = blockIdx.x * blockDim.x + threadIdx.x;
    if (b < B_ROWS) {
        int z = (int)(unsigned int)(best[b] & 0xFFFFFFFFull);
        atomicMax(&winner[z], b);
    }
}

__global__ __launch_bounds__(256) void write_out(
    const float* __restrict__ y, const float* __restrict__ m,
    const float* __restrict__ sd, const int* __restrict__ winner,
    float* __restrict__ out) {
    const int idx = blockIdx.x;
    const int t = threadIdx.x;
    const int w = winner[idx];
    const float4* mp = (const float4*)(m + (size_t)idx * KDIM);
    const float4* sp = (const float4*)(sd + (size_t)idx * KDIM);
    float4* om = (float4*)(out + (size_t)idx * KDIM);
    float4* os = (float4*)(out + (size_t)(N_CLUST + idx) * KDIM);
    if (w >= 0) {
        const float4* yp = (const float4*)(y + (size_t)w * KDIM);
        for (int i = t; i < KDIM / 4; i += 256) {
            float4 mv = mp[i], yv = yp[i], sv = sp[i];
            float4 nm, ns;
            nm.x = mv.x * EMA_OLD + yv.x * EMA_NEW;
            nm.y = mv.y * EMA_OLD + yv.y * EMA_NEW;
            nm.z = mv.z * EMA_OLD + yv.z * EMA_NEW;
            nm.w = mv.w * EMA_OLD + yv.w * EMA_NEW;
            float dx = nm.x - yv.x, dy = nm.y - yv.y;
            float dz = nm.z - yv.z, dw = nm.w - yv.w;
            ns.x = dx * dx * EMA_OLD + sv.x * EMA_NEW;
            ns.y = dy * dy * EMA_OLD + sv.y * EMA_NEW;
            ns.z = dz * dz * EMA_OLD + sv.z * EMA_NEW;
            ns.w = dw * dw * EMA_OLD + sv.w * EMA_NEW;
            om[i] = nm;
            os[i] = ns;
        }
    } else {
        for (int i = t; i < KDIM / 4; i += 256) {
            om[i] = mp[i];
            os[i] = sp[i];
        }
    }
}

extern "C" void kernel_launch(void* const* d_in, const int* in_sizes, int n_in,
                              void* d_out, int out_size, void* d_ws,
                              size_t ws_size, hipStream_t stream) {
    const float* y  = (const float*)d_in[0];
    const float* m  = (const float*)d_in[1];
    const float* sd = (const float*)d_in[2];
    float* out = (float*)d_out;

    char* ws = (char*)d_ws;
    unsigned long long* best = (unsigned long long*)(ws + WS_BEST_OFF);
    int* winner = (int*)(ws + WS_WINNER_OFF);
    float* yy   = (float*)(ws + WS_YY_OFF);
    float* mm   = (float*)(ws + WS_MM_OFF);

    // best = u64 max, winner = -1, in one async memset (graph-capture safe)
    hipMemsetAsync(ws, 0xFF, 36864, stream);

    rowsumsq_all<<<(B_ROWS + N_CLUST) * 64 / 256, 256, 0, stream>>>(y, m, yy, mm);

    if (ws_size >= (size_t)WS_REQUIRED) {
        ushortT* yhi = (ushortT*)(ws + WS_YHI_OFF);
        ushortT* ylo = (ushortT*)(ws + WS_YLO_OFF);
        ushortT* mhi = (ushortT*)(ws + WS_MHI_OFF);
        ushortT* mlo = (ushortT*)(ws + WS_MLO_OFF);

        convert_all<<<(YCHUNKS + MCHUNKS) / 256, 256, 0, stream>>>(
            y, m, yhi, ylo, mhi, mlo);

        dim3 grid(B_ROWS / 64, N_CLUST / 64);
        dist_argmin_mfma<<<grid, 256, 0, stream>>>(yhi, ylo, mhi, mlo, yy, mm, best);
    } else {
        dim3 grid(B_ROWS / BM, N_CLUST / BN);
        dist_argmin_fp32<<<grid, 256, 0, stream>>>(y, m, yy, mm, best);
    }

    pick_winner<<<B_ROWS / 256, 256, 0, stream>>>(best, winner);
    write_out<<<N_CLUST, 256, 0, stream>>>(y, m, sd, winner, out);
}

// Round 5
// 286.669 us; speedup vs baseline: 1.0511x; 1.0511x over previous
//
#include <hip/hip_runtime.h>

#define B_ROWS 4096
#define N_CLUST 1024
#define KDIM 4096
#define KT2 128        // k-tiles of 32

#define EMA_OLD 0.01f
#define EMA_NEW 0.99f

typedef unsigned short ushortT;
typedef _Float16 half8 __attribute__((ext_vector_type(8)));
typedef float f32x16 __attribute__((ext_vector_type(16)));

// ---------------- workspace layout (bytes) ----------------
#define WS_BEST_OFF   0
#define WS_WINNER_OFF 32768
#define WS_YY_OFF     36864
#define WS_MM_OFF     53248
#define WS_YHI_OFF    65536
#define WS_YLO_OFF    (WS_YHI_OFF + 33554432)
#define WS_MHI_OFF    (WS_YLO_OFF + 33554432)
#define WS_MLO_OFF    (WS_MHI_OFF + 8388608)
#define WS_REQUIRED   (WS_MLO_OFF + 8388608)  // ~84.2 MB

// ---------------- fused f16 hi/lo split + row sum-of-squares ----------------
// Tiled layout: block (rb, kt2) of R rows x 32 halfs contiguous; within a
// half-row, 16B chunk at logical c stored at physical p = c ^ (r&3).
// One block per source row; 512 chunks/row, 2 per thread.
__global__ __launch_bounds__(256) void convert_sumsq(
    const float* __restrict__ ysrc, const float* __restrict__ msrc,
    ushortT* __restrict__ yhi, ushortT* __restrict__ ylo,
    ushortT* __restrict__ mhi, ushortT* __restrict__ mlo,
    float* __restrict__ yy, float* __restrict__ mm) {
    const int blk = blockIdx.x;
    const float* src;
    ushortT *hi, *lo;
    float* out;
    int row, r, rb, rows;
    if (blk < B_ROWS) {
        src = ysrc; hi = yhi; lo = ylo; out = yy + blk;
        row = blk; r = row & 127; rb = row >> 7; rows = 128;
    } else {
        int rm = blk - B_ROWS;
        src = msrc; hi = mhi; lo = mlo; out = mm + rm;
        row = rm; r = row & 63; rb = row >> 6; rows = 64;
    }
    const int t = threadIdx.x;
    float s = 0.f;
#pragma unroll
    for (int h = 0; h < 2; ++h) {
        int ci = h * 256 + t;        // chunk index in row [0,512)
        int kt2 = ci >> 2, p = ci & 3;
        int c = p ^ (r & 3);
        const float* sp = src + ((size_t)row << 12) + kt2 * 32 + c * 8;
        float4 v0 = *(const float4*)sp;
        float4 v1 = *(const float4*)(sp + 4);
        float vv[8] = {v0.x, v0.y, v0.z, v0.w, v1.x, v1.y, v1.z, v1.w};
        half8 hv, lv;
#pragma unroll
        for (int i = 0; i < 8; ++i) {
            _Float16 hh = (_Float16)vv[i];
            hv[i] = hh;
            lv[i] = (_Float16)(vv[i] - (float)hh);
            s += vv[i] * vv[i];
        }
        size_t off = ((size_t)rb * KT2 + kt2) * ((size_t)rows * 32)
                   + (size_t)r * 32 + p * 8;
        *(half8*)(hi + off) = hv;
        *(half8*)(lo + off) = lv;
    }
    for (int off = 32; off > 0; off >>= 1) s += __shfl_down(s, off, 64);
    __shared__ float red[4];
    if ((t & 63) == 0) red[t >> 6] = s;
    __syncthreads();
    if (t == 0) out[0] = red[0] + red[1] + red[2] + red[3];
}

// ---------------- MFMA distance + fused argmin ----------------
__device__ __forceinline__ void gload_lds16(const void* g, void* l) {
    __builtin_amdgcn_global_load_lds(
        (const __attribute__((address_space(1))) unsigned int*)g,
        (__attribute__((address_space(3))) unsigned int*)l, 16, 0, 0);
}

__device__ __forceinline__ half8 ldfrag32(const ushortT* s, int r, int c) {
    int p = c ^ (r & 3);
    return *(const half8*)(s + r * 32 + p * 8);
}

#define MFMA_HH(a, b, c) __builtin_amdgcn_mfma_f32_32x32x16_f16(a, b, c, 0, 0, 0)

// 128x128 block tile, BK=32, double-buffered 2x32 KB LDS, 1 block/CU.
// 4 waves, wave tile 64x64 (2x2 of 32x32). Grid 256, by = blockIdx&7 (XCD).
__global__ __launch_bounds__(256, 1) void dist_argmin_mfma(
    const ushortT* __restrict__ Ah, const ushortT* __restrict__ Al,
    const ushortT* __restrict__ Bh, const ushortT* __restrict__ Bl,
    const float* __restrict__ yy, const float* __restrict__ mm,
    unsigned long long* __restrict__ best) {
    __shared__ __align__(16) char smem[65536];
    // per buffer (32 KB): sAh @0 (8K), sAl @8K, sBh @16K, sBl @24K

    const int t = threadIdx.x, w = t >> 6, l = t & 63;
    const int bx = blockIdx.x >> 3, by = blockIdx.x & 7;
    const int row0 = bx * 128, col0 = by * 128;
    const int wr = (w >> 1) * 64, wc = (w & 1) * 64;
    const int m0 = l & 31, hsel = l >> 5;
    const size_t jb0 = 2 * (size_t)by;

    const char* gAh = (const char*)Ah + (size_t)bx * (KT2 * 8192) + l * 16;
    const char* gAl = (const char*)Al + (size_t)bx * (KT2 * 8192) + l * 16;
    const char* gBh = (const char*)Bh + l * 16;
    const char* gBl = (const char*)Bl + l * 16;

    f32x16 acc00, acc01, acc10, acc11;
#pragma unroll
    for (int i = 0; i < 16; ++i) {
        acc00[i] = 0.f; acc01[i] = 0.f; acc10[i] = 0.f; acc11[i] = 0.f;
    }

    // stage one BK=32 tile (32 KB) into buffer `buf`: 8 chunks each of
    // A-hi/A-lo/B-hi/B-lo, wave w loads chunks w*2, w*2+1 of each.
    auto stage = [&](int buf, int kt2) {
        char* bs = smem + buf * 32768;
        size_t aoff = (size_t)kt2 * 8192;
#pragma unroll
        for (int j = 0; j < 2; ++j) {
            int ch = w * 2 + j;
            gload_lds16(gAh + aoff + ch * 1024, bs + ch * 1024);
            gload_lds16(gAl + aoff + ch * 1024, bs + 8192 + ch * 1024);
            size_t boff = ((jb0 + (ch >> 2)) * KT2 + kt2) * 4096 + (ch & 3) * 1024;
            gload_lds16(gBh + boff, bs + 16384 + ch * 1024);
            gload_lds16(gBl + boff, bs + 24576 + ch * 1024);
        }
    };

    stage(0, 0);
    for (int kt2 = 0; kt2 < KT2; ++kt2) {
        const int cur = kt2 & 1;
        __syncthreads();               // cur's loads drained (issued last iter)
        if (kt2 + 1 < KT2) stage(cur ^ 1, kt2 + 1);   // prefetch next tile
        const ushortT* sAh = (const ushortT*)(smem + cur * 32768);
        const ushortT* sAl = (const ushortT*)(smem + cur * 32768 + 8192);
        const ushortT* sBh = (const ushortT*)(smem + cur * 32768 + 16384);
        const ushortT* sBl = (const ushortT*)(smem + cur * 32768 + 24576);
#pragma unroll
        for (int kk = 0; kk < 2; ++kk) {
            int c = kk * 2 + hsel;
            half8 ah0 = ldfrag32(sAh, wr + m0, c);
            half8 ah1 = ldfrag32(sAh, wr + 32 + m0, c);
            half8 al0 = ldfrag32(sAl, wr + m0, c);
            half8 al1 = ldfrag32(sAl, wr + 32 + m0, c);
            half8 bh0 = ldfrag32(sBh, wc + m0, c);
            half8 bh1 = ldfrag32(sBh, wc + 32 + m0, c);
            half8 bl0 = ldfrag32(sBl, wc + m0, c);
            half8 bl1 = ldfrag32(sBl, wc + 32 + m0, c);
            // per-element chain order hh,hl,lh — identical to rounds 2-4
            acc00 = MFMA_HH(ah0, bh0, acc00);
            acc01 = MFMA_HH(ah0, bh1, acc01);
            acc10 = MFMA_HH(ah1, bh0, acc10);
            acc11 = MFMA_HH(ah1, bh1, acc11);
            acc00 = MFMA_HH(ah0, bl0, acc00);
            acc01 = MFMA_HH(ah0, bl1, acc01);
            acc10 = MFMA_HH(ah1, bl0, acc10);
            acc11 = MFMA_HH(ah1, bl1, acc11);
            acc00 = MFMA_HH(al0, bh0, acc00);
            acc01 = MFMA_HH(al0, bh1, acc01);
            acc10 = MFMA_HH(al1, bh0, acc10);
            acc11 = MFMA_HH(al1, bh1, acc11);
        }
        __syncthreads();               // all reads of cur done before overwrite
    }

    // ---- epilogue: d2 + in-register argmin, 32 cols per lane-pair ----
    const int gc0 = col0 + wc + m0;
    const int gc1 = col0 + wc + 32 + m0;
    const float mv0 = mm[gc0], mv1 = mm[gc1];
    {   // rows wr .. wr+31 (acc00 / acc01)
        unsigned long long key[16];
#pragma unroll
        for (int r = 0; r < 16; ++r) {
            int ri = (r & 3) + 8 * (r >> 2) + 4 * hsel;
            float yv = yy[row0 + wr + ri];
            float da = yv - 2.0f * acc00[r] + mv0;
            float db = yv - 2.0f * acc01[r] + mv1;
            unsigned long long ka =
                ((unsigned long long)__float_as_uint(da) << 32) | (unsigned)gc0;
            unsigned long long kb =
                ((unsigned long long)__float_as_uint(db) << 32) | (unsigned)gc1;
            key[r] = kb < ka ? kb : ka;
        }
#pragma unroll
        for (int s = 1; s <= 16; s <<= 1)
#pragma unroll
            for (int r = 0; r < 16; ++r) {
                unsigned long long o = __shfl_xor(key[r], s, 64);
                if (o < key[r]) key[r] = o;
            }
        if (m0 == 0)
#pragma unroll
            for (int r = 0; r < 16; ++r) {
                int ri = (r & 3) + 8 * (r >> 2) + 4 * hsel;
                atomicMin(&best[row0 + wr + ri], key[r]);
            }
    }
    {   // rows wr+32 .. wr+63 (acc10 / acc11)
        unsigned long long key[16];
#pragma unroll
        for (int r = 0; r < 16; ++r) {
            int ri = (r & 3) + 8 * (r >> 2) + 4 * hsel;
            float yv = yy[row0 + wr + 32 + ri];
            float da = yv - 2.0f * acc10[r] + mv0;
            float db = yv - 2.0f * acc11[r] + mv1;
            unsigned long long ka =
                ((unsigned long long)__float_as_uint(da) << 32) | (unsigned)gc0;
            unsigned long long kb =
                ((unsigned long long)__float_as_uint(db) << 32) | (unsigned)gc1;
            key[r] = kb < ka ? kb : ka;
        }
#pragma unroll
        for (int s = 1; s <= 16; s <<= 1)
#pragma unroll
            for (int r = 0; r < 16; ++r) {
                unsigned long long o = __shfl_xor(key[r], s, 64);
                if (o < key[r]) key[r] = o;
            }
        if (m0 == 0)
#pragma unroll
            for (int r = 0; r < 16; ++r) {
                int ri = (r & 3) + 8 * (r >> 2) + 4 * hsel;
                atomicMin(&best[row0 + wr + 32 + ri], key[r]);
            }
    }
}

// ---------------- scatter + output ----------------
__global__ void pick_winner(const unsigned long long* __restrict__ best,
                            int* __restrict__ winner) {
    int b = blockIdx.x * blockDim.x + threadIdx.x;
    if (b < B_ROWS) {
        int z = (int)(unsigned int)(best[b] & 0xFFFFFFFFull);
        atomicMax(&winner[z], b);
    }
}

__global__ __launch_bounds__(256) void write_out(
    const float* __restrict__ y, const float* __restrict__ m,
    const float* __restrict__ sd, const int* __restrict__ winner,
    float* __restrict__ out) {
    const int idx = blockIdx.x;
    const int t = threadIdx.x;
    const int w = winner[idx];
    const float4* mp = (const float4*)(m + (size_t)idx * KDIM);
    const float4* sp = (const float4*)(sd + (size_t)idx * KDIM);
    float4* om = (float4*)(out + (size_t)idx * KDIM);
    float4* os = (float4*)(out + (size_t)(N_CLUST + idx) * KDIM);
    if (w >= 0) {
        const float4* yp = (const float4*)(y + (size_t)w * KDIM);
        for (int i = t; i < KDIM / 4; i += 256) {
            float4 mv = mp[i], yv = yp[i], sv = sp[i];
            float4 nm, ns;
            nm.x = mv.x * EMA_OLD + yv.x * EMA_NEW;
            nm.y = mv.y * EMA_OLD + yv.y * EMA_NEW;
            nm.z = mv.z * EMA_OLD + yv.z * EMA_NEW;
            nm.w = mv.w * EMA_OLD + yv.w * EMA_NEW;
            float dx = nm.x - yv.x, dy = nm.y - yv.y;
            float dz = nm.z - yv.z, dw = nm.w - yv.w;
            ns.x = dx * dx * EMA_OLD + sv.x * EMA_NEW;
            ns.y = dy * dy * EMA_OLD + sv.y * EMA_NEW;
            ns.z = dz * dz * EMA_OLD + sv.z * EMA_NEW;
            ns.w = dw * dw * EMA_OLD + sv.w * EMA_NEW;
            om[i] = nm;
            os[i] = ns;
        }
    } else {
        for (int i = t; i < KDIM / 4; i += 256) {
            om[i] = mp[i];
            os[i] = sp[i];
        }
    }
}

extern "C" void kernel_launch(void* const* d_in, const int* in_sizes, int n_in,
                              void* d_out, int out_size, void* d_ws,
                              size_t ws_size, hipStream_t stream) {
    const float* y  = (const float*)d_in[0];
    const float* m  = (const float*)d_in[1];
    const float* sd = (const float*)d_in[2];
    float* out = (float*)d_out;

    char* ws = (char*)d_ws;
    unsigned long long* best = (unsigned long long*)(ws + WS_BEST_OFF);
    int* winner = (int*)(ws + WS_WINNER_OFF);
    float* yy   = (float*)(ws + WS_YY_OFF);
    float* mm   = (float*)(ws + WS_MM_OFF);

    ushortT* yhi = (ushortT*)(ws + WS_YHI_OFF);
    ushortT* ylo = (ushortT*)(ws + WS_YLO_OFF);
    ushortT* mhi = (ushortT*)(ws + WS_MHI_OFF);
    ushortT* mlo = (ushortT*)(ws + WS_MLO_OFF);

    // best = u64 max, winner = -1, in one async memset (graph-capture safe)
    hipMemsetAsync(ws, 0xFF, 36864, stream);

    convert_sumsq<<<B_ROWS + N_CLUST, 256, 0, stream>>>(
        y, m, yhi, ylo, mhi, mlo, yy, mm);

    dist_argmin_mfma<<<256, 256, 0, stream>>>(yhi, ylo, mhi, mlo, yy, mm, best);

    pick_winner<<<B_ROWS / 256, 256, 0, stream>>>(best, winner);
    write_out<<<N_CLUST, 256, 0, stream>>>(y, m, sd, winner, out);
}

// Round 6
// 225.403 us; speedup vs baseline: 1.3368x; 1.2718x over previous
//
#include <hip/hip_runtime.h>

#define B_ROWS 4096
#define N_CLUST 1024
#define KDIM 4096
#define NKT 32          // k-tiles of 128 halfs

#define EMA_OLD 0.01f
#define EMA_NEW 0.99f
#define MARGIN 2.0f     // screen d2 error max ~0.27 (40 sigma headroom)

typedef unsigned short ushortT;
typedef _Float16 half8 __attribute__((ext_vector_type(8)));
typedef float f32x16 __attribute__((ext_vector_type(16)));

// ---------------- workspace layout (bytes) ----------------
#define WS_WINNER_OFF 0                  // i32[1024], memset 0xFF
#define WS_Z_OFF      4096               // i32[4096]
#define WS_YY_OFF     20480              // f32[4096]
#define WS_MM_OFF     36864              // f32[1024]
#define WS_D2_OFF     65536              // f32[4096*1024] = 16 MiB
#define WS_YHI_OFF    (WS_D2_OFF + 16777216)     // 33.5 MB
#define WS_MHI_OFF    (WS_YHI_OFF + 33554432)    // 8.4 MB
#define WS_END        (WS_MHI_OFF + 8388608)     // ~58.8 MB

// ---------------- fused f16-hi convert + row sum-of-squares ----------------
// Tiled layout: block (rb, kt) of 64 rows x 128 halfs contiguous (16 KB).
// Within a row (16 chunks of 16B), logical chunk c stored at p = c ^ (r&15).
// One 256-thread block per source row; 512 chunks/row, 2 per thread.
__global__ __launch_bounds__(256) void convert_sumsq(
    const float* __restrict__ ysrc, const float* __restrict__ msrc,
    ushortT* __restrict__ yhi, ushortT* __restrict__ mhi,
    float* __restrict__ yy, float* __restrict__ mm) {
    const int blk = blockIdx.x;
    const float* src;
    ushortT* hi;
    float* out;
    int row;
    if (blk < B_ROWS) {
        src = ysrc; hi = yhi; out = yy + blk; row = blk;
    } else {
        row = blk - B_ROWS;
        src = msrc; hi = mhi; out = mm + row;
    }
    const int r = row & 63, rb = row >> 6;
    const int t = threadIdx.x;
    float s = 0.f;
#pragma unroll
    for (int h = 0; h < 2; ++h) {
        int ci = h * 256 + t;        // physical chunk in row [0,512)
        int kt = ci >> 4, p = ci & 15;
        int c = p ^ (r & 15);
        const float* sp = src + ((size_t)row << 12) + kt * 128 + c * 8;
        float4 v0 = *(const float4*)sp;
        float4 v1 = *(const float4*)(sp + 4);
        float vv[8] = {v0.x, v0.y, v0.z, v0.w, v1.x, v1.y, v1.z, v1.w};
        half8 hv;
#pragma unroll
        for (int i = 0; i < 8; ++i) {
            hv[i] = (_Float16)vv[i];
            s += vv[i] * vv[i];
        }
        size_t off = (((size_t)rb * NKT + kt) * 64 + r) * 128 + p * 8;
        *(half8*)(hi + off) = hv;
    }
    for (int off = 32; off > 0; off >>= 1) s += __shfl_down(s, off, 64);
    __shared__ float red[4];
    if ((t & 63) == 0) red[t >> 6] = s;
    __syncthreads();
    if (t == 0) out[0] = red[0] + red[1] + red[2] + red[3];
}

// ---------------- screen GEMM: d2_screen = yy - 2*Yhi@Mhi^T + mm ----------
__device__ __forceinline__ void gload_lds16(const void* g, void* l) {
    __builtin_amdgcn_global_load_lds(
        (const __attribute__((address_space(1))) unsigned int*)g,
        (__attribute__((address_space(3))) unsigned int*)l, 16, 0, 0);
}

__device__ __forceinline__ half8 ldfrag(const ushortT* s, int r, int c) {
    int p = c ^ (r & 15);
    return *(const half8*)(s + r * 128 + p * 8);
}

// 64x64 block tile, BK=128, 32 KB LDS, grid 1024 (4 blocks/CU).
// 4 waves = 2x2 of 32x32 tiles; per kt: 8 gload + 16 ds_read_b128 + 8 MFMA/wave.
__global__ __launch_bounds__(256, 4) void screen_gemm(
    const ushortT* __restrict__ Ah, const ushortT* __restrict__ Bh,
    const float* __restrict__ yy, const float* __restrict__ mm,
    float* __restrict__ d2ws) {
    __shared__ __align__(16) ushortT sA[64 * 128];   // 16 KB
    __shared__ __align__(16) ushortT sB[64 * 128];   // 16 KB

    const int t = threadIdx.x, w = t >> 6, l = t & 63;
    const int bx = blockIdx.x >> 4, by = blockIdx.x & 15;
    const int row0 = bx * 64, col0 = by * 64;
    const int wr = (w >> 1) * 32, wc = (w & 1) * 32;
    const int m0 = l & 31, hsel = l >> 5;

    const char* gA = (const char*)Ah + (size_t)bx * (NKT * 16384) + l * 16;
    const char* gB = (const char*)Bh + (size_t)by * (NKT * 16384) + l * 16;

    f32x16 acc;
#pragma unroll
    for (int i = 0; i < 16; ++i) acc[i] = 0.f;

    for (int kt = 0; kt < NKT; ++kt) {
        __syncthreads();
#pragma unroll
        for (int j = 0; j < 4; ++j) {
            int ch = w * 4 + j;
            gload_lds16(gA + (size_t)kt * 16384 + ch * 1024, (char*)sA + ch * 1024);
            gload_lds16(gB + (size_t)kt * 16384 + ch * 1024, (char*)sB + ch * 1024);
        }
        __syncthreads();
#pragma unroll
        for (int kk = 0; kk < 8; ++kk) {
            int c = kk * 2 + hsel;
            half8 ah = ldfrag(sA, wr + m0, c);
            half8 bh = ldfrag(sB, wc + m0, c);
            acc = __builtin_amdgcn_mfma_f32_32x32x16_f16(ah, bh, acc, 0, 0, 0);
        }
    }

    const int gcol = col0 + wc + m0;
    const float mv = mm[gcol];
#pragma unroll
    for (int r = 0; r < 16; ++r) {
        int ri = (r & 3) + 8 * (r >> 2) + 4 * hsel;
        int grow = row0 + wr + ri;
        d2ws[(size_t)grow * N_CLUST + gcol] = yy[grow] - 2.0f * acc[r] + mv;
    }
}

// ---------------- rescreen: exact argmin per row ----------------
// One wave per row. Scan 1024 screen distances; candidates within MARGIN of
// the row min. 1 candidate -> it's the argmin. Else exact double-acc dots.
__global__ __launch_bounds__(256) void rescreen(
    const float* __restrict__ d2ws, const float* __restrict__ ysrc,
    const float* __restrict__ msrc, const float* __restrict__ yy,
    const float* __restrict__ mm, int* __restrict__ z) {
    const int row = blockIdx.x * 4 + (threadIdx.x >> 6);
    const int l = threadIdx.x & 63;
    const float* dr = d2ws + (size_t)row * N_CLUST;

    float v[16];
#pragma unroll
    for (int k = 0; k < 16; ++k) v[k] = dr[l + 64 * k];

    float mn = v[0];
#pragma unroll
    for (int k = 1; k < 16; ++k) mn = fminf(mn, v[k]);
#pragma unroll
    for (int s = 1; s <= 32; s <<= 1) mn = fminf(mn, __shfl_xor(mn, s, 64));
    const float thr = mn + MARGIN;

    int cnt = 0;
#pragma unroll
    for (int k = 0; k < 16; ++k) cnt += (v[k] <= thr) ? 1 : 0;
#pragma unroll
    for (int s = 1; s <= 32; s <<= 1) cnt += __shfl_xor(cnt, s, 64);

    int zj;
    if (cnt == 1) {
        int cj = 0x7FFFFFFF;
#pragma unroll
        for (int k = 0; k < 16; ++k)
            if (v[k] <= thr) cj = min(cj, l + 64 * k);
#pragma unroll
        for (int s = 1; s <= 32; s <<= 1) cj = min(cj, __shfl_xor(cj, s, 64));
        zj = cj;
    } else {
        double bestd = 1e300;
        int bestj = -1;
        const float4* yp = (const float4*)(ysrc + (size_t)row * KDIM);
        for (int k = 0; k < 16; ++k) {
            unsigned long long mask = __ballot(v[k] <= thr);
            while (mask) {
                int lb = __ffsll((unsigned long long)mask) - 1;
                mask &= mask - 1;
                int j = 64 * k + lb;
                const float4* mp = (const float4*)(msrc + (size_t)j * KDIM);
                double acc = 0.0;
#pragma unroll
                for (int tt = 0; tt < 16; ++tt) {
                    float4 a = yp[l + 64 * tt];
                    float4 b = mp[l + 64 * tt];
                    acc += (double)a.x * b.x + (double)a.y * b.y +
                           (double)a.z * b.z + (double)a.w * b.w;
                }
#pragma unroll
                for (int s = 1; s <= 32; s <<= 1)
                    acc += __shfl_xor(acc, s, 64);
                double d2x = (double)yy[row] - 2.0 * acc + (double)mm[j];
                if (d2x < bestd) { bestd = d2x; bestj = j; }  // strict: low j wins ties
            }
        }
        zj = bestj;
    }
    if (l == 0) z[row] = zj;
}

// ---------------- scatter + output ----------------
__global__ void pick_winner(const int* __restrict__ z,
                            int* __restrict__ winner) {
    int b = blockIdx.x * blockDim.x + threadIdx.x;
    if (b < B_ROWS) atomicMax(&winner[z[b]], b);
}

__global__ __launch_bounds__(256) void write_out(
    const float* __restrict__ y, const float* __restrict__ m,
    const float* __restrict__ sd, const int* __restrict__ winner,
    float* __restrict__ out) {
    const int idx = blockIdx.x;
    const int t = threadIdx.x;
    const int w = winner[idx];
    const float4* mp = (const float4*)(m + (size_t)idx * KDIM);
    const float4* sp = (const float4*)(sd + (size_t)idx * KDIM);
    float4* om = (float4*)(out + (size_t)idx * KDIM);
    float4* os = (float4*)(out + (size_t)(N_CLUST + idx) * KDIM);
    if (w >= 0) {
        const float4* yp = (const float4*)(y + (size_t)w * KDIM);
        for (int i = t; i < KDIM / 4; i += 256) {
            float4 mv = mp[i], yv = yp[i], sv = sp[i];
            float4 nm, ns;
            nm.x = mv.x * EMA_OLD + yv.x * EMA_NEW;
            nm.y = mv.y * EMA_OLD + yv.y * EMA_NEW;
            nm.z = mv.z * EMA_OLD + yv.z * EMA_NEW;
            nm.w = mv.w * EMA_OLD + yv.w * EMA_NEW;
            float dx = nm.x - yv.x, dy = nm.y - yv.y;
            float dz = nm.z - yv.z, dw = nm.w - yv.w;
            ns.x = dx * dx * EMA_OLD + sv.x * EMA_NEW;
            ns.y = dy * dy * EMA_OLD + sv.y * EMA_NEW;
            ns.z = dz * dz * EMA_OLD + sv.z * EMA_NEW;
            ns.w = dw * dw * EMA_OLD + sv.w * EMA_NEW;
            om[i] = nm;
            os[i] = ns;
        }
    } else {
        for (int i = t; i < KDIM / 4; i += 256) {
            om[i] = mp[i];
            os[i] = sp[i];
        }
    }
}

extern "C" void kernel_launch(void* const* d_in, const int* in_sizes, int n_in,
                              void* d_out, int out_size, void* d_ws,
                              size_t ws_size, hipStream_t stream) {
    const float* y  = (const float*)d_in[0];
    const float* m  = (const float*)d_in[1];
    const float* sd = (const float*)d_in[2];
    float* out = (float*)d_out;

    char* ws = (char*)d_ws;
    int* winner = (int*)(ws + WS_WINNER_OFF);
    int* z      = (int*)(ws + WS_Z_OFF);
    float* yy   = (float*)(ws + WS_YY_OFF);
    float* mm   = (float*)(ws + WS_MM_OFF);
    float* d2ws = (float*)(ws + WS_D2_OFF);
    ushortT* yhi = (ushortT*)(ws + WS_YHI_OFF);
    ushortT* mhi = (ushortT*)(ws + WS_MHI_OFF);

    hipMemsetAsync(winner, 0xFF, 4096, stream);   // winner = -1

    convert_sumsq<<<B_ROWS + N_CLUST, 256, 0, stream>>>(y, m, yhi, mhi, yy, mm);

    screen_gemm<<<(B_ROWS / 64) * (N_CLUST / 64), 256, 0, stream>>>(
        yhi, mhi, yy, mm, d2ws);

    rescreen<<<B_ROWS / 4, 256, 0, stream>>>(d2ws, y, m, yy, mm, z);

    pick_winner<<<B_ROWS / 256, 256, 0, stream>>>(z, winner);
    write_out<<<N_CLUST, 256, 0, stream>>>(y, m, sd, winner, out);
}